// Round 4
// baseline (196.723 us; speedup 1.0000x reference)
//
#include <hip/hip_runtime.h>

// QRNN forget-mult: h_t = i_t*z_t + f_t*h_{t-1}, T=4096, B=32, H=256, fp32.
// Chunked parallel scan over T: partial (local scan + product), carry scan, final apply.

constexpr int T   = 4096;
constexpr int CHN = 32 * 256;   // 8192 channels (B*H)
constexpr int C4  = CHN / 4;    // 2048 float4-channels

// ---------------- kernel 1: per-chunk local recurrence + forget product ----------------
template <int NC>
__global__ __launch_bounds__(256) void qrnn_partial(
    const float4* __restrict__ f, const float4* __restrict__ z,
    const float4* __restrict__ ig,
    float4* __restrict__ Ps, float4* __restrict__ Hs) {
  constexpr int CL = T / NC;
  const int c4    = blockIdx.x * 256 + threadIdx.x;   // float4-channel id
  const int chunk = blockIdx.y;
  int idx = chunk * CL * C4 + c4;
  float4 h = make_float4(0.f, 0.f, 0.f, 0.f);
  float4 P = make_float4(1.f, 1.f, 1.f, 1.f);
#pragma unroll 8
  for (int t = 0; t < CL; ++t) {
    const float4 ft = f[idx];
    const float4 zt = z[idx];
    const float4 it = ig[idx];
    h.x = fmaf(ft.x, h.x, it.x * zt.x);
    h.y = fmaf(ft.y, h.y, it.y * zt.y);
    h.z = fmaf(ft.z, h.z, it.z * zt.z);
    h.w = fmaf(ft.w, h.w, it.w * zt.w);
    P.x *= ft.x; P.y *= ft.y; P.z *= ft.z; P.w *= ft.w;
    idx += C4;
  }
  Ps[chunk * C4 + c4] = P;
  Hs[chunk * C4 + c4] = h;
}

// ---------------- kernel 2: sequential scan over chunk summaries ----------------
// After this kernel, Hs[k] holds the hidden state ENTERING chunk k.
template <int NC>
__global__ __launch_bounds__(256) void qrnn_scan(
    const float4* __restrict__ hinit,
    const float4* __restrict__ Ps, float4* __restrict__ Hs) {
  const int c4 = blockIdx.x * 256 + threadIdx.x;
  float4 carry = hinit[c4];  // h entering chunk 0
  for (int k = 0; k < NC; ++k) {
    const int idx = k * C4 + c4;
    const float4 P  = Ps[idx];
    const float4 Hl = Hs[idx];
    Hs[idx] = carry;
    carry.x = fmaf(P.x, carry.x, Hl.x);
    carry.y = fmaf(P.y, carry.y, Hl.y);
    carry.z = fmaf(P.z, carry.z, Hl.z);
    carry.w = fmaf(P.w, carry.w, Hl.w);
  }
}

// ---------------- kernel 3: recompute chunk from exact carry, write output ----------------
template <int NC>
__global__ __launch_bounds__(256) void qrnn_final(
    const float4* __restrict__ f, const float4* __restrict__ z,
    const float4* __restrict__ ig, const float4* __restrict__ Hs,
    float4* __restrict__ out) {
  constexpr int CL = T / NC;
  const int c4    = blockIdx.x * 256 + threadIdx.x;
  const int chunk = blockIdx.y;
  int idx = chunk * CL * C4 + c4;
  float4 h = Hs[chunk * C4 + c4];
#pragma unroll 8
  for (int t = 0; t < CL; ++t) {
    const float4 ft = f[idx];
    const float4 zt = z[idx];
    const float4 it = ig[idx];
    h.x = fmaf(ft.x, h.x, it.x * zt.x);
    h.y = fmaf(ft.y, h.y, it.y * zt.y);
    h.z = fmaf(ft.z, h.z, it.z * zt.z);
    h.w = fmaf(ft.w, h.w, it.w * zt.w);
    out[idx] = h;
    idx += C4;
  }
}

template <int NC>
static void launch_all(const float4* f, const float4* z, const float4* ig,
                       const float4* hinit, float4* out, void* ws,
                       hipStream_t stream) {
  float4* Ps = (float4*)ws;
  float4* Hs = (float4*)((char*)ws + (size_t)NC * CHN * sizeof(float));
  dim3 blk(256);
  dim3 g13(C4 / 256, NC);   // (8, NC)
  dim3 g2(C4 / 256);        // (8)
  qrnn_partial<NC><<<g13, blk, 0, stream>>>(f, z, ig, Ps, Hs);
  qrnn_scan<NC><<<g2, blk, 0, stream>>>(hinit, Ps, Hs);
  qrnn_final<NC><<<g13, blk, 0, stream>>>(f, z, ig, Hs, out);
}

extern "C" void kernel_launch(void* const* d_in, const int* in_sizes, int n_in,
                              void* d_out, int out_size, void* d_ws, size_t ws_size,
                              hipStream_t stream) {
  const float4* f     = (const float4*)d_in[0];
  const float4* z     = (const float4*)d_in[1];
  const float4* ig    = (const float4*)d_in[2];
  const float4* hinit = (const float4*)d_in[3];
  float4* out = (float4*)d_out;

  const size_t need64 = 2ull * 64 * CHN * sizeof(float);  // 4 MiB
  if (ws_size >= need64) {
    launch_all<64>(f, z, ig, hinit, out, d_ws, stream);
  } else {
    launch_all<16>(f, z, ig, hinit, out, d_ws, stream);   // 1 MiB summaries
  }
}

// Round 6
// 189.412 us; speedup vs baseline: 1.0386x; 1.0386x over previous
//
#include <hip/hip_runtime.h>

// QRNN forget-mult: h_t = i_t*z_t + f_t*h_{t-1}, T=4096, B=32, H=256, fp32.
// Chunked parallel scan over T. Round 6: register-batched loads (U timesteps
// issued before any use) to break the latency serialization seen in Round 4
// (VGPR=36, 1.7 TB/s). Nontemporal out-store via native clang vector type
// (HIP float4 is a class -> rejected by the builtin, Round-5 compile fail).

constexpr int T   = 4096;
constexpr int CHN = 32 * 256;   // 8192 channels (B*H)
constexpr int C4  = CHN / 4;    // 2048 float4-channels

typedef float v4f __attribute__((ext_vector_type(4)));

__device__ __forceinline__ void fma4(float4& h, const float4& ft, const float4& zt,
                                     const float4& it) {
  h.x = fmaf(ft.x, h.x, it.x * zt.x);
  h.y = fmaf(ft.y, h.y, it.y * zt.y);
  h.z = fmaf(ft.z, h.z, it.z * zt.z);
  h.w = fmaf(ft.w, h.w, it.w * zt.w);
}

// ---------------- kernel 1: per-chunk local recurrence + forget product ----------------
template <int NC, int U>
__global__ __launch_bounds__(256) void qrnn_partial(
    const float4* __restrict__ f, const float4* __restrict__ z,
    const float4* __restrict__ ig,
    float4* __restrict__ Ps, float4* __restrict__ Hs) {
  constexpr int CL = T / NC;
  static_assert(CL % U == 0, "");
  const int c4    = blockIdx.x * 256 + threadIdx.x;
  const int chunk = blockIdx.y;
  int idx = chunk * CL * C4 + c4;
  float4 h = make_float4(0.f, 0.f, 0.f, 0.f);
  float4 P = make_float4(1.f, 1.f, 1.f, 1.f);
  for (int body = 0; body < CL / U; ++body) {
    float4 rf[U], rz[U], ri[U];
#pragma unroll
    for (int u = 0; u < U; ++u) {
      rf[u] = f[idx + u * C4];
      rz[u] = z[idx + u * C4];
      ri[u] = ig[idx + u * C4];
    }
#pragma unroll
    for (int u = 0; u < U; ++u) {
      fma4(h, rf[u], rz[u], ri[u]);
      P.x *= rf[u].x; P.y *= rf[u].y; P.z *= rf[u].z; P.w *= rf[u].w;
    }
    idx += U * C4;
  }
  Ps[chunk * C4 + c4] = P;
  Hs[chunk * C4 + c4] = h;
}

// ---------------- kernel 2: sequential scan over chunk summaries ----------------
// After this kernel, Hs[k] holds the hidden state ENTERING chunk k.
template <int NC>
__global__ __launch_bounds__(256) void qrnn_scan(
    const float4* __restrict__ hinit,
    const float4* __restrict__ Ps, float4* __restrict__ Hs) {
  const int c4 = blockIdx.x * 256 + threadIdx.x;
  float4 carry = hinit[c4];
  constexpr int US = 4;
  for (int k0 = 0; k0 < NC; k0 += US) {
    float4 rp[US], rh[US];
#pragma unroll
    for (int u = 0; u < US; ++u) {
      rp[u] = Ps[(k0 + u) * C4 + c4];
      rh[u] = Hs[(k0 + u) * C4 + c4];
    }
#pragma unroll
    for (int u = 0; u < US; ++u) {
      Hs[(k0 + u) * C4 + c4] = carry;
      carry.x = fmaf(rp[u].x, carry.x, rh[u].x);
      carry.y = fmaf(rp[u].y, carry.y, rh[u].y);
      carry.z = fmaf(rp[u].z, carry.z, rh[u].z);
      carry.w = fmaf(rp[u].w, carry.w, rh[u].w);
    }
  }
}

// ---------------- kernel 3: recompute chunk from exact carry, write output ----------------
template <int NC, int U>
__global__ __launch_bounds__(256) void qrnn_final(
    const float4* __restrict__ f, const float4* __restrict__ z,
    const float4* __restrict__ ig, const float4* __restrict__ Hs,
    float4* __restrict__ out) {
  constexpr int CL = T / NC;
  static_assert(CL % U == 0, "");
  const int c4    = blockIdx.x * 256 + threadIdx.x;
  const int chunk = blockIdx.y;
  int idx = chunk * CL * C4 + c4;
  float4 h = Hs[chunk * C4 + c4];
  v4f* __restrict__ outv = (v4f*)out;
  for (int body = 0; body < CL / U; ++body) {
    float4 rf[U], rz[U], ri[U];
#pragma unroll
    for (int u = 0; u < U; ++u) {
      rf[u] = f[idx + u * C4];
      rz[u] = z[idx + u * C4];
      ri[u] = ig[idx + u * C4];
    }
#pragma unroll
    for (int u = 0; u < U; ++u) {
      fma4(h, rf[u], rz[u], ri[u]);
      // nontemporal: out is never re-read; keep f/z/i resident in LLC instead.
      v4f hv = {h.x, h.y, h.z, h.w};
      __builtin_nontemporal_store(hv, &outv[idx + u * C4]);
    }
    idx += U * C4;
  }
}

template <int NC>
static void launch_all(const float4* f, const float4* z, const float4* ig,
                       const float4* hinit, float4* out, void* ws,
                       hipStream_t stream) {
  float4* Ps = (float4*)ws;
  float4* Hs = (float4*)((char*)ws + (size_t)NC * CHN * sizeof(float));
  dim3 blk(256);
  dim3 g13(C4 / 256, NC);   // (8, NC)
  dim3 g2(C4 / 256);        // (8)
  qrnn_partial<NC, 8><<<g13, blk, 0, stream>>>(f, z, ig, Ps, Hs);
  qrnn_scan<NC><<<g2, blk, 0, stream>>>(hinit, Ps, Hs);
  qrnn_final<NC, 8><<<g13, blk, 0, stream>>>(f, z, ig, Hs, out);
}

extern "C" void kernel_launch(void* const* d_in, const int* in_sizes, int n_in,
                              void* d_out, int out_size, void* d_ws, size_t ws_size,
                              hipStream_t stream) {
  const float4* f     = (const float4*)d_in[0];
  const float4* z     = (const float4*)d_in[1];
  const float4* ig    = (const float4*)d_in[2];
  const float4* hinit = (const float4*)d_in[3];
  float4* out = (float4*)d_out;

  const size_t need64 = 2ull * 64 * CHN * sizeof(float);  // 4 MiB
  if (ws_size >= need64) {
    launch_all<64>(f, z, ig, hinit, out, d_ws, stream);
  } else {
    launch_all<16>(f, z, ig, hinit, out, d_ws, stream);   // 1 MiB summaries
  }
}